// Round 4
// baseline (306.384 us; speedup 1.0000x reference)
//
#include <hip/hip_runtime.h>

#define NSET 48
#define NITEM 128
#define DIM 256
#define HEADS 4
#define NROWS (NSET * NITEM)   // 6144 rows per source

typedef _Float16 f16;
typedef _Float16 f16x8 __attribute__((ext_vector_type(8)));
typedef _Float16 f16x4 __attribute__((ext_vector_type(4)));
typedef float    f32x4 __attribute__((ext_vector_type(4)));

// ---- workspace layout (bytes) ----
static constexpr size_t OFF_XYH = 6291456;
static constexpr size_t OFF_WT  = 12582912;
static constexpr size_t OFF_LXY = 12713984;

// ---------------- prep: W transpose + fp16 ----------------
__global__ __launch_bounds__(256) void k_wt(const float* __restrict__ W,
                                            f16* __restrict__ WT) {
  int c = blockIdx.x, d = threadIdx.x;
  WT[c * DIM + d] = (f16)W[d * DIM + c];
}

// ---------------- prep: row l2-normalize + fp16 casts ----------------
__global__ __launch_bounds__(256) void k_norm(const float* __restrict__ x,
                                              const float* __restrict__ y,
                                              f16* __restrict__ XYN,
                                              f16* __restrict__ XYH) {
  int row  = blockIdx.x * 4 + (threadIdx.x >> 6);   // one wave per 256-elem row
  int lane = threadIdx.x & 63;
  const float* src = (row < NROWS) ? (x + (size_t)row * DIM)
                                   : (y + (size_t)(row - NROWS) * DIM);
  float4 v = *(const float4*)(src + lane * 4);
  float ss = v.x * v.x + v.y * v.y + v.z * v.z + v.w * v.w;
  #pragma unroll
  for (int off = 32; off >= 1; off >>= 1) ss += __shfl_xor(ss, off);
  float rn = 1.0f / sqrtf(fmaxf(ss, 1e-12f));       // tf.nn.l2_normalize semantics
  f16x4 hn = { (f16)(v.x * rn), (f16)(v.y * rn), (f16)(v.z * rn), (f16)(v.w * rn) };
  f16x4 hr = { (f16)v.x, (f16)v.y, (f16)v.z, (f16)v.w };
  *(f16x4*)(XYN + (size_t)row * DIM + lane * 4) = hn;
  *(f16x4*)(XYH + (size_t)row * DIM + lane * 4) = hr;
}

// ---------------- prep: projection GEMM  LXY[R][c] = XYH[R][:] . WT[c][:] ----------------
// No LDS: fragments loaded global->VGPR (tiles are L2-resident).
// A = WT rows (c), B = XYH rows (R) => D[row=c][col=R]; lane holds 4
// consecutive c at fixed R -> vector f16x4 store into LXY[R][c].
__global__ __launch_bounds__(256, 4) void k_proj(const f16* __restrict__ XYH,
                                                 const f16* __restrict__ WT,
                                                 f16* __restrict__ LXY) {
  const int bid = blockIdx.x, rt = bid >> 1, ct = bid & 1;   // 96 row-tiles x 2 col-tiles
  const int tid = threadIdx.x, w = tid >> 6, lane = tid & 63;
  const int wR = (w >> 1) * 64;        // R range within 128-row tile
  const int wC = (w & 1) * 64;         // c range within 128-col tile
  const int la = lane & 15, lb = lane >> 4;

  const f16* pa[4];
  const f16* pb[4];
  #pragma unroll
  for (int m = 0; m < 4; ++m)
    pa[m] = WT + (size_t)(ct * 128 + wC + m * 16 + la) * DIM + (lb << 3);
  #pragma unroll
  for (int n = 0; n < 4; ++n)
    pb[n] = XYH + (size_t)(rt * 128 + wR + n * 16 + la) * DIM + (lb << 3);

  f32x4 acc[4][4] = {};
  #pragma unroll
  for (int k0 = 0; k0 < DIM; k0 += 32) {
    f16x8 a[4], b[4];
    #pragma unroll
    for (int m = 0; m < 4; ++m) a[m] = *(const f16x8*)(pa[m] + k0);
    #pragma unroll
    for (int n = 0; n < 4; ++n) b[n] = *(const f16x8*)(pb[n] + k0);
    #pragma unroll
    for (int m = 0; m < 4; ++m)
      #pragma unroll
      for (int n = 0; n < 4; ++n)
        acc[m][n] = __builtin_amdgcn_mfma_f32_16x16x32_f16(a[m], b[n], acc[m][n], 0, 0, 0);
  }
  #pragma unroll
  for (int m = 0; m < 4; ++m)          // c tiles (row dim of D)
    #pragma unroll
    for (int n = 0; n < 4; ++n) {      // R tiles (col dim of D)
      int R = rt * 128 + wR + n * 16 + la;
      int c = ct * 128 + wC + m * 16 + lb * 4;
      f16x4 hv = { (f16)acc[m][n][0], (f16)acc[m][n][1],
                   (f16)acc[m][n][2], (f16)acc[m][n][3] };
      *(f16x4*)(LXY + (size_t)R * DIM + c) = hv;
    }
}

// ---------------- main: per (y,x) pair -> cos_sim tile + score ----------------
// Fragment reads stay global->VGPR (inputs L2/L3-resident). out0 epilogue is
// transposed through a 32KB LDS half-tile so global stores are FULL 512B rows
// (1KB per wave-instruction, non-temporal) -> each out0 cache line is written
// exactly once, fully, and never allocates in L2. This kills the R2/R3 write
// amplification (WRITE 790MB -> 152MB) caused by 64MB of concurrent
// partial-line tiles thrashing 32MB of L2.
__global__ __launch_bounds__(256, 4) void k_main(const f16* __restrict__ XYN,
                                                 const f16* __restrict__ LXY,
                                                 const float* __restrict__ nItem,
                                                 const float* __restrict__ w2,
                                                 float* __restrict__ out0,
                                                 float* __restrict__ out1) {
  __shared__ float hbuf[64 * 128];     // 32KB: half of the 128x128 f32 tile (rows=i)
  __shared__ float red[4][4];
  const int bid = blockIdx.x;
  const int ys = bid / NSET, xs = bid % NSET;
  const int tid = threadIdx.x, w = tid >> 6, lane = tid & 63;
  const int wj = (w >> 1) * 64;        // j (y item) range -> A operand
  const int wi = (w & 1) * 64;         // i (x item) range -> B operand
  const int la = lane & 15, lb = lane >> 4;

  // ---- phase 1: cos_sim[y, x, i, j] = xn[x,i,:] . yn[y,j,:]  (D[j][i]) ----
  f32x4 acc[4][4];
  {
    const f16* ybase = XYN + (size_t)(NROWS + ys * NITEM) * DIM;
    const f16* xbase = XYN + (size_t)(xs * NITEM) * DIM;
    const f16* pa[4];
    const f16* pb[4];
    #pragma unroll
    for (int m = 0; m < 4; ++m)
      pa[m] = ybase + (size_t)(wj + m * 16 + la) * DIM + (lb << 3);
    #pragma unroll
    for (int n = 0; n < 4; ++n)
      pb[n] = xbase + (size_t)(wi + n * 16 + la) * DIM + (lb << 3);

    #pragma unroll
    for (int m = 0; m < 4; ++m)
      #pragma unroll
      for (int n = 0; n < 4; ++n) acc[m][n] = (f32x4){0.f, 0.f, 0.f, 0.f};
    #pragma unroll
    for (int k0 = 0; k0 < DIM; k0 += 32) {
      f16x8 a[4], b[4];
      #pragma unroll
      for (int m = 0; m < 4; ++m) a[m] = *(const f16x8*)(pa[m] + k0);
      #pragma unroll
      for (int n = 0; n < 4; ++n) b[n] = *(const f16x8*)(pb[n] + k0);
      #pragma unroll
      for (int m = 0; m < 4; ++m)
        #pragma unroll
        for (int n = 0; n < 4; ++n)
          acc[m][n] = __builtin_amdgcn_mfma_f32_16x16x32_f16(a[m], b[n], acc[m][n], 0, 0, 0);
    }
  }

  // ---- epilogue: LDS-transpose per 64-row half, stream full rows out ----
  float* base = out0 + (size_t)(ys * NSET + xs) * NITEM * NITEM;
  #pragma unroll
  for (int half = 0; half < 2; ++half) {
    if ((w & 1) == half) {             // waves owning i-range [half*64, half*64+64)
      #pragma unroll
      for (int m = 0; m < 4; ++m)
        #pragma unroll
        for (int n = 0; n < 4; ++n) {
          int il = n * 16 + la;                     // local i: 0..63
          int jb = (wj + m * 16 + lb * 4) * 4;      // byte offset along j
          *(f32x4*)((char*)hbuf + il * 512 + (jb ^ ((il & 15) << 4))) = acc[m][n];
        }
    }
    __syncthreads();
    #pragma unroll
    for (int c = 0; c < 8; ++c) {      // each wave streams 16 rows, 2 rows/instr
      int il = w * 16 + c * 2 + (lane >> 5);
      int jb = (lane & 31) * 16;
      f32x4 v = *(const f32x4*)((char*)hbuf + il * 512 + (jb ^ ((il & 15) << 4)));
      __builtin_nontemporal_store(v, (f32x4*)(base + (size_t)(half * 64 + il) * NITEM) + (lane & 31));
    }
    __syncthreads();
  }

  // ---- phase 2: scores. s[h] = sum_ij relu(lx[i,h*64:].ly[j,h*64:]) ----
  {
    const f16* ybase = LXY + (size_t)(NROWS + ys * NITEM) * DIM;
    const f16* xbase = LXY + (size_t)(xs * NITEM) * DIM;
    const f16* pa[4];
    const f16* pb[4];
    #pragma unroll
    for (int m = 0; m < 4; ++m)
      pa[m] = ybase + (size_t)(wj + m * 16 + la) * DIM + (lb << 3);
    #pragma unroll
    for (int n = 0; n < 4; ++n)
      pb[n] = xbase + (size_t)(wi + n * 16 + la) * DIM + (lb << 3);

    float rsum[HEADS];
    #pragma unroll
    for (int h = 0; h < HEADS; ++h) {
      f32x4 acc2[4][4] = {};
      #pragma unroll
      for (int kk = 0; kk < 2; ++kk) {           // K=64 per head; relu AFTER full K
        int k0 = h * 64 + kk * 32;
        f16x8 a[4], b[4];
        #pragma unroll
        for (int m = 0; m < 4; ++m) a[m] = *(const f16x8*)(pa[m] + k0);
        #pragma unroll
        for (int n = 0; n < 4; ++n) b[n] = *(const f16x8*)(pb[n] + k0);
        #pragma unroll
        for (int m = 0; m < 4; ++m)
          #pragma unroll
          for (int n = 0; n < 4; ++n)
            acc2[m][n] = __builtin_amdgcn_mfma_f32_16x16x32_f16(a[m], b[n], acc2[m][n], 0, 0, 0);
      }
      float s = 0.f;
      #pragma unroll
      for (int m = 0; m < 4; ++m)
        #pragma unroll
        for (int n = 0; n < 4; ++n)
          #pragma unroll
          for (int r = 0; r < 4; ++r) s += fmaxf(acc2[m][n][r], 0.f);
      rsum[h] = s;
    }
    #pragma unroll
    for (int off = 32; off >= 1; off >>= 1)
      #pragma unroll
      for (int h = 0; h < HEADS; ++h) rsum[h] += __shfl_xor(rsum[h], off);
    if (lane == 0) {
      #pragma unroll
      for (int h = 0; h < HEADS; ++h) red[w][h] = rsum[h];
    }
  }
  __syncthreads();
  if (tid == 0) {
    // relu(S/8) summed == (sum relu(S))/8 ; then / nItem[x] / nItem[y]; then @ w2
    float inv = 1.0f / (8.0f * nItem[xs] * nItem[ys]);
    float sc = 0.f;
    #pragma unroll
    for (int h = 0; h < HEADS; ++h)
      sc += (red[0][h] + red[1][h] + red[2][h] + red[3][h]) * inv * w2[h];
    out1[ys * NSET + xs] = sc;
  }
}

// ---------------- launch ----------------
extern "C" void kernel_launch(void* const* d_in, const int* in_sizes, int n_in,
                              void* d_out, int out_size, void* d_ws, size_t ws_size,
                              hipStream_t stream) {
  const float* x     = (const float*)d_in[0];
  const float* y     = (const float*)d_in[1];
  const float* nItem = (const float*)d_in[2];
  const float* W     = (const float*)d_in[3];
  const float* w2    = (const float*)d_in[4];
  float* out0 = (float*)d_out;
  float* out1 = out0 + (size_t)NSET * NSET * NITEM * NITEM;

  char* ws = (char*)d_ws;
  f16* XYN = (f16*)ws;
  f16* XYH = (f16*)(ws + OFF_XYH);
  f16* WT  = (f16*)(ws + OFF_WT);
  f16* LXY = (f16*)(ws + OFF_LXY);

  k_wt<<<256, 256, 0, stream>>>(W, WT);
  k_norm<<<(2 * NROWS) / 4, 256, 0, stream>>>(x, y, XYN, XYH);
  k_proj<<<192, 256, 0, stream>>>(XYH, WT, LXY);
  k_main<<<NSET * NSET, 256, 0, stream>>>(XYN, LXY, nItem, w2, out0, out1);
}

// Round 5
// 173.351 us; speedup vs baseline: 1.7674x; 1.7674x over previous
//
#include <hip/hip_runtime.h>

#define NSET 48
#define NITEM 128
#define DIM 256
#define HEADS 4
#define NROWS (NSET * NITEM)   // 6144 rows per source

typedef _Float16 f16;
typedef _Float16 f16x8 __attribute__((ext_vector_type(8)));
typedef _Float16 f16x4 __attribute__((ext_vector_type(4)));
typedef float    f32x4 __attribute__((ext_vector_type(4)));

// ---- workspace layout (bytes) ----
static constexpr size_t OFF_XYH = 6291456;
static constexpr size_t OFF_WT  = 12582912;
static constexpr size_t OFF_LXY = 12713984;

// ---------------- prep: W transpose + fp16 ----------------
__global__ __launch_bounds__(256) void k_wt(const float* __restrict__ W,
                                            f16* __restrict__ WT) {
  int c = blockIdx.x, d = threadIdx.x;
  WT[c * DIM + d] = (f16)W[d * DIM + c];
}

// ---------------- prep: row l2-normalize + fp16 casts ----------------
__global__ __launch_bounds__(256) void k_norm(const float* __restrict__ x,
                                              const float* __restrict__ y,
                                              f16* __restrict__ XYN,
                                              f16* __restrict__ XYH) {
  int row  = blockIdx.x * 4 + (threadIdx.x >> 6);   // one wave per 256-elem row
  int lane = threadIdx.x & 63;
  const float* src = (row < NROWS) ? (x + (size_t)row * DIM)
                                   : (y + (size_t)(row - NROWS) * DIM);
  float4 v = *(const float4*)(src + lane * 4);
  float ss = v.x * v.x + v.y * v.y + v.z * v.z + v.w * v.w;
  #pragma unroll
  for (int off = 32; off >= 1; off >>= 1) ss += __shfl_xor(ss, off);
  float rn = 1.0f / sqrtf(fmaxf(ss, 1e-12f));       // tf.nn.l2_normalize semantics
  f16x4 hn = { (f16)(v.x * rn), (f16)(v.y * rn), (f16)(v.z * rn), (f16)(v.w * rn) };
  f16x4 hr = { (f16)v.x, (f16)v.y, (f16)v.z, (f16)v.w };
  *(f16x4*)(XYN + (size_t)row * DIM + lane * 4) = hn;
  *(f16x4*)(XYH + (size_t)row * DIM + lane * 4) = hr;
}

// ---------------- prep: projection GEMM  LXY[R][c] = XYH[R][:] . WT[c][:] ----------------
// (256,2): <=256 unified regs -> no scratch spill (the R2-R4 lesson).
__global__ __launch_bounds__(256, 2) void k_proj(const f16* __restrict__ XYH,
                                                 const f16* __restrict__ WT,
                                                 f16* __restrict__ LXY) {
  const int bid = blockIdx.x, rt = bid >> 1, ct = bid & 1;   // 96 row-tiles x 2 col-tiles
  const int tid = threadIdx.x, w = tid >> 6, lane = tid & 63;
  const int wR = (w >> 1) * 64;        // R range within 128-row tile
  const int wC = (w & 1) * 64;         // c range within 128-col tile
  const int la = lane & 15, lb = lane >> 4;

  const f16* pa[4];
  const f16* pb[4];
  #pragma unroll
  for (int m = 0; m < 4; ++m)
    pa[m] = WT + (size_t)(ct * 128 + wC + m * 16 + la) * DIM + (lb << 3);
  #pragma unroll
  for (int n = 0; n < 4; ++n)
    pb[n] = XYH + (size_t)(rt * 128 + wR + n * 16 + la) * DIM + (lb << 3);

  f32x4 acc[4][4] = {};
  #pragma unroll
  for (int k0 = 0; k0 < DIM; k0 += 32) {
    f16x8 a[4], b[4];
    #pragma unroll
    for (int m = 0; m < 4; ++m) a[m] = *(const f16x8*)(pa[m] + k0);
    #pragma unroll
    for (int n = 0; n < 4; ++n) b[n] = *(const f16x8*)(pb[n] + k0);
    #pragma unroll
    for (int m = 0; m < 4; ++m)
      #pragma unroll
      for (int n = 0; n < 4; ++n)
        acc[m][n] = __builtin_amdgcn_mfma_f32_16x16x32_f16(a[m], b[n], acc[m][n], 0, 0, 0);
  }
  #pragma unroll
  for (int m = 0; m < 4; ++m)          // c tiles (row dim of D)
    #pragma unroll
    for (int n = 0; n < 4; ++n) {      // R tiles (col dim of D)
      int R = rt * 128 + wR + n * 16 + la;
      int c = ct * 128 + wC + m * 16 + lb * 4;
      f16x4 hv = { (f16)acc[m][n][0], (f16)acc[m][n][1],
                   (f16)acc[m][n][2], (f16)acc[m][n][3] };
      *(f16x4*)(LXY + (size_t)R * DIM + c) = hv;
    }
}

// ---------------- cos_sim kernel: one block per (ys,xs) ----------------
// Phase-split from the old k_main: the two phases shared no inputs, and the
// fused live-set under a (256,4) reg cap spilled to scratch (R2-R4: 760MB
// WRITE / 360MB FETCH = spill traffic). (256,2) + split keeps everything in
// registers. Epilogue transposes through 32KB LDS so global stores are full
// 512B rows, non-temporal (output never pollutes L2).
__global__ __launch_bounds__(256, 2) void k_cos(const f16* __restrict__ XYN,
                                                float* __restrict__ out0) {
  __shared__ float hbuf[64 * 128];     // 32KB: half of the 128x128 f32 tile
  const int bid = blockIdx.x;
  const int ys = bid / NSET, xs = bid % NSET;
  const int tid = threadIdx.x, w = tid >> 6, lane = tid & 63;
  const int wj = (w >> 1) * 64;        // j (y item) range -> A operand
  const int wi = (w & 1) * 64;         // i (x item) range -> B operand
  const int la = lane & 15, lb = lane >> 4;

  const f16* ybase = XYN + (size_t)(NROWS + ys * NITEM) * DIM;
  const f16* xbase = XYN + (size_t)(xs * NITEM) * DIM;
  const f16* pa[4];
  const f16* pb[4];
  #pragma unroll
  for (int m = 0; m < 4; ++m)
    pa[m] = ybase + (size_t)(wj + m * 16 + la) * DIM + (lb << 3);
  #pragma unroll
  for (int n = 0; n < 4; ++n)
    pb[n] = xbase + (size_t)(wi + n * 16 + la) * DIM + (lb << 3);

  f32x4 acc[4][4] = {};
  #pragma unroll
  for (int k0 = 0; k0 < DIM; k0 += 32) {
    f16x8 a[4], b[4];
    #pragma unroll
    for (int m = 0; m < 4; ++m) a[m] = *(const f16x8*)(pa[m] + k0);
    #pragma unroll
    for (int n = 0; n < 4; ++n) b[n] = *(const f16x8*)(pb[n] + k0);
    #pragma unroll
    for (int m = 0; m < 4; ++m)
      #pragma unroll
      for (int n = 0; n < 4; ++n)
        acc[m][n] = __builtin_amdgcn_mfma_f32_16x16x32_f16(a[m], b[n], acc[m][n], 0, 0, 0);
  }

  // epilogue: per 64-row half, LDS-transpose then stream full rows out
  float* base = out0 + (size_t)(ys * NSET + xs) * NITEM * NITEM;
  #pragma unroll
  for (int half = 0; half < 2; ++half) {
    if ((w & 1) == half) {             // waves owning i-range [half*64, half*64+64)
      #pragma unroll
      for (int m = 0; m < 4; ++m)
        #pragma unroll
        for (int n = 0; n < 4; ++n) {
          int il = n * 16 + la;                     // local i: 0..63
          int jb = (wj + m * 16 + lb * 4) * 4;      // byte offset along j
          *(f32x4*)((char*)hbuf + il * 512 + (jb ^ ((il & 15) << 4))) = acc[m][n];
        }
    }
    __syncthreads();
    #pragma unroll
    for (int c = 0; c < 8; ++c) {      // each wave streams 16 rows, 2 rows/instr
      int il = w * 16 + c * 2 + (lane >> 5);
      int jb = (lane & 31) * 16;
      f32x4 v = *(const f32x4*)((char*)hbuf + il * 512 + (jb ^ ((il & 15) << 4)));
      __builtin_nontemporal_store(v, (f32x4*)(base + (size_t)(half * 64 + il) * NITEM) + (lane & 31));
    }
    __syncthreads();
  }
}

// ---------------- score kernel: one block per (ys,xs) ----------------
__global__ __launch_bounds__(256, 2) void k_score(const f16* __restrict__ LXY,
                                                  const float* __restrict__ nItem,
                                                  const float* __restrict__ w2,
                                                  float* __restrict__ out1) {
  __shared__ float red[4][4];
  const int bid = blockIdx.x;
  const int ys = bid / NSET, xs = bid % NSET;
  const int tid = threadIdx.x, w = tid >> 6, lane = tid & 63;
  const int wj = (w >> 1) * 64;        // j (y item) range -> A operand
  const int wi = (w & 1) * 64;         // i (x item) range -> B operand
  const int la = lane & 15, lb = lane >> 4;

  const f16* ybase = LXY + (size_t)(NROWS + ys * NITEM) * DIM;
  const f16* xbase = LXY + (size_t)(xs * NITEM) * DIM;
  const f16* pa[4];
  const f16* pb[4];
  #pragma unroll
  for (int m = 0; m < 4; ++m)
    pa[m] = ybase + (size_t)(wj + m * 16 + la) * DIM + (lb << 3);
  #pragma unroll
  for (int n = 0; n < 4; ++n)
    pb[n] = xbase + (size_t)(wi + n * 16 + la) * DIM + (lb << 3);

  float rsum[HEADS];
  #pragma unroll
  for (int h = 0; h < HEADS; ++h) {
    f32x4 acc[4][4] = {};
    #pragma unroll
    for (int kk = 0; kk < 2; ++kk) {             // K=64 per head; relu AFTER full K
      int k0 = h * 64 + kk * 32;
      f16x8 a[4], b[4];
      #pragma unroll
      for (int m = 0; m < 4; ++m) a[m] = *(const f16x8*)(pa[m] + k0);
      #pragma unroll
      for (int n = 0; n < 4; ++n) b[n] = *(const f16x8*)(pb[n] + k0);
      #pragma unroll
      for (int m = 0; m < 4; ++m)
        #pragma unroll
        for (int n = 0; n < 4; ++n)
          acc[m][n] = __builtin_amdgcn_mfma_f32_16x16x32_f16(a[m], b[n], acc[m][n], 0, 0, 0);
    }
    float s = 0.f;
    #pragma unroll
    for (int m = 0; m < 4; ++m)
      #pragma unroll
      for (int n = 0; n < 4; ++n)
        #pragma unroll
        for (int r = 0; r < 4; ++r) s += fmaxf(acc[m][n][r], 0.f);
    rsum[h] = s;
  }
  #pragma unroll
  for (int off = 32; off >= 1; off >>= 1)
    #pragma unroll
    for (int h = 0; h < HEADS; ++h) rsum[h] += __shfl_xor(rsum[h], off);
  if (lane == 0) {
    #pragma unroll
    for (int h = 0; h < HEADS; ++h) red[w][h] = rsum[h];
  }
  __syncthreads();
  if (tid == 0) {
    // relu(S/8) summed == (sum relu(S))/8 ; then / nItem[x] / nItem[y]; then @ w2
    float inv = 1.0f / (8.0f * nItem[xs] * nItem[ys]);
    float sc = 0.f;
    #pragma unroll
    for (int h = 0; h < HEADS; ++h)
      sc += (red[0][h] + red[1][h] + red[2][h] + red[3][h]) * inv * w2[h];
    out1[ys * NSET + xs] = sc;
  }
}

// ---------------- launch ----------------
extern "C" void kernel_launch(void* const* d_in, const int* in_sizes, int n_in,
                              void* d_out, int out_size, void* d_ws, size_t ws_size,
                              hipStream_t stream) {
  const float* x     = (const float*)d_in[0];
  const float* y     = (const float*)d_in[1];
  const float* nItem = (const float*)d_in[2];
  const float* W     = (const float*)d_in[3];
  const float* w2    = (const float*)d_in[4];
  float* out0 = (float*)d_out;
  float* out1 = out0 + (size_t)NSET * NSET * NITEM * NITEM;

  char* ws = (char*)d_ws;
  f16* XYN = (f16*)ws;
  f16* XYH = (f16*)(ws + OFF_XYH);
  f16* WT  = (f16*)(ws + OFF_WT);
  f16* LXY = (f16*)(ws + OFF_LXY);

  k_wt<<<256, 256, 0, stream>>>(W, WT);
  k_norm<<<(2 * NROWS) / 4, 256, 0, stream>>>(x, y, XYN, XYH);
  k_proj<<<192, 256, 0, stream>>>(XYH, WT, LXY);
  k_cos<<<NSET * NSET, 256, 0, stream>>>(XYN, out0);
  k_score<<<NSET * NSET, 256, 0, stream>>>(LXY, nItem, w2, out1);
}

// Round 6
// 122.027 us; speedup vs baseline: 2.5108x; 1.4206x over previous
//
#include <hip/hip_runtime.h>

#define NSET 48
#define NITEM 128
#define DIM 256
#define HEADS 4
#define NROWS (NSET * NITEM)   // 6144 rows per source

typedef _Float16 f16;
typedef _Float16 f16x8 __attribute__((ext_vector_type(8)));
typedef _Float16 f16x4 __attribute__((ext_vector_type(4)));
typedef float    f32x4 __attribute__((ext_vector_type(4)));

// ---- fragment-major layout ----
// A source matrix is stored per 128-row "set" (32768 halves = 64KB). Within a
// set: 64 chunks of 512 halves (1KB), chunk = (r/16)*8 + (k/32). Within a
// chunk, lane-slot l (16B) holds row r = rbase+(l&15), halves kbase+(l>>4)*8..+8
// -- exactly the mfma_16x16x32 A/B fragment for that (row-block, k-block).
// So an operand fragment load is ONE lane-contiguous 1KB wave-load instead of
// 16 scattered 64B segments (the R5 L1-transaction bottleneck: 16 lines/instr).
#define SETH 32768   // halves per set
__device__ __forceinline__ int faddr(int r, int k) {   // in halves, within a set
  return ((r >> 4) * 8 + (k >> 5)) * 512 + ((((k >> 3) & 3) * 16 + (r & 15)) * 8) + (k & 7);
}

// ---- workspace layout (bytes) ----
// XYN_F  96 sets (x:0..47, y:48..95)  @ 0         6 MB  (normalized, frag-major)
// XYH_F  96 sets                      @ 0x600000  6 MB  (raw fp16, frag-major)
// WT_F   2 sets (rows=c, k=d)         @ 0xC00000  128KB (W^T, frag-major)
// LXY_F  96 sets (rows=R, k=c)        @ 0xC20000  6 MB  (projection, frag-major)
static constexpr size_t OFF_XYH = 6291456;
static constexpr size_t OFF_WT  = 12582912;
static constexpr size_t OFF_LXY = 12713984;

// ---------------- prep: W transpose + fp16, frag-major ----------------
// block d = W row; thread c: read W[d][c] coalesced, scatter 2B into WT_F.
__global__ __launch_bounds__(256) void k_wt(const float* __restrict__ W,
                                            f16* __restrict__ WT_F) {
  int d = blockIdx.x, c = threadIdx.x;
  WT_F[(c >> 7) * SETH + faddr(c & 127, d)] = (f16)W[d * DIM + c];
}

// ---------------- prep: row l2-normalize + fp16 casts, frag-major ----------------
__global__ __launch_bounds__(256) void k_norm(const float* __restrict__ x,
                                              const float* __restrict__ y,
                                              f16* __restrict__ XYN_F,
                                              f16* __restrict__ XYH_F) {
  int rg   = blockIdx.x * 4 + (threadIdx.x >> 6);   // global row 0..12287
  int lane = threadIdx.x & 63;
  const float* src = (rg < NROWS) ? (x + (size_t)rg * DIM)
                                  : (y + (size_t)(rg - NROWS) * DIM);
  float4 v = *(const float4*)(src + lane * 4);
  float ss = v.x * v.x + v.y * v.y + v.z * v.z + v.w * v.w;
  #pragma unroll
  for (int off = 32; off >= 1; off >>= 1) ss += __shfl_xor(ss, off);
  float rn = 1.0f / sqrtf(fmaxf(ss, 1e-12f));       // tf.nn.l2_normalize semantics
  f16x4 hn = { (f16)(v.x * rn), (f16)(v.y * rn), (f16)(v.z * rn), (f16)(v.w * rn) };
  f16x4 hr = { (f16)v.x, (f16)v.y, (f16)v.z, (f16)v.w };
  int dst = (rg >> 7) * SETH + faddr(rg & 127, lane * 4);   // (lane*4)&7 in {0,4}: 8B slot
  *(f16x4*)(XYN_F + dst) = hn;
  *(f16x4*)(XYH_F + dst) = hr;
}

// ---------------- prep: projection GEMM  LXY[R][c] = XYH[R][:] . WT[c][:] ----------------
// All operands frag-major; every inner load is a contiguous 1KB wave-load.
__global__ __launch_bounds__(256, 2) void k_proj(const f16* __restrict__ XYH_F,
                                                 const f16* __restrict__ WT_F,
                                                 f16* __restrict__ LXY_F) {
  const int bid = blockIdx.x, rt = bid >> 1, ct = bid & 1;   // 96 row-sets x 2 col-tiles
  const int tid = threadIdx.x, w = tid >> 6, lane = tid & 63;
  const int wR = (w >> 1) * 64;        // R range within set
  const int wC = (w & 1) * 64;         // c range within 128-col tile
  const int la = lane & 15, lb = lane >> 4;

  const f16* pa[4];                    // A = WT rows (c), set ct
  const f16* pb[4];                    // B = XYH rows (R), set rt
  #pragma unroll
  for (int m = 0; m < 4; ++m)
    pa[m] = WT_F + ct * SETH + ((wC >> 4) + m) * 4096 + lane * 8;
  #pragma unroll
  for (int n = 0; n < 4; ++n)
    pb[n] = XYH_F + rt * SETH + ((wR >> 4) + n) * 4096 + lane * 8;

  f32x4 acc[4][4] = {};
  #pragma unroll
  for (int k0 = 0; k0 < DIM; k0 += 32) {
    const int ko = (k0 >> 5) * 512;
    f16x8 a[4], b[4];
    #pragma unroll
    for (int m = 0; m < 4; ++m) a[m] = *(const f16x8*)(pa[m] + ko);
    #pragma unroll
    for (int n = 0; n < 4; ++n) b[n] = *(const f16x8*)(pb[n] + ko);
    #pragma unroll
    for (int m = 0; m < 4; ++m)
      #pragma unroll
      for (int n = 0; n < 4; ++n)
        acc[m][n] = __builtin_amdgcn_mfma_f32_16x16x32_f16(a[m], b[n], acc[m][n], 0, 0, 0);
  }
  // D[row=c][col=R]: lane holds 4 consecutive c at fixed R -> 8B frag-major write
  #pragma unroll
  for (int m = 0; m < 4; ++m)
    #pragma unroll
    for (int n = 0; n < 4; ++n) {
      int rloc = wR + n * 16 + la;               // R within set rt
      int c0   = ct * 128 + wC + m * 16 + lb * 4;
      f16x4 hv = { (f16)acc[m][n][0], (f16)acc[m][n][1],
                   (f16)acc[m][n][2], (f16)acc[m][n][3] };
      *(f16x4*)(LXY_F + rt * SETH + faddr(rloc, c0)) = hv;
    }
}

// ---------------- cos_sim kernel: one block per (ys,xs) ----------------
// Frag-major reads (1KB/instr). Epilogue transposes through 32KB LDS so global
// stores are full 512B rows, non-temporal (R4 lesson kept; R2-R4 spill lesson:
// phase-split + (256,2)).
__global__ __launch_bounds__(256, 2) void k_cos(const f16* __restrict__ XYN_F,
                                                float* __restrict__ out0) {
  __shared__ float hbuf[64 * 128];     // 32KB: half of the 128x128 f32 tile
  const int bid = blockIdx.x;
  const int ys = bid / NSET, xs = bid % NSET;
  const int tid = threadIdx.x, w = tid >> 6, lane = tid & 63;
  const int wj = (w >> 1) * 64;        // j (y item) range -> A operand
  const int wi = (w & 1) * 64;         // i (x item) range -> B operand
  const int la = lane & 15, lb = lane >> 4;

  const f16* pa[4];
  const f16* pb[4];
  #pragma unroll
  for (int m = 0; m < 4; ++m)
    pa[m] = XYN_F + (48 + ys) * SETH + ((wj >> 4) + m) * 4096 + lane * 8;
  #pragma unroll
  for (int n = 0; n < 4; ++n)
    pb[n] = XYN_F + xs * SETH + ((wi >> 4) + n) * 4096 + lane * 8;

  f32x4 acc[4][4] = {};
  #pragma unroll
  for (int k0 = 0; k0 < DIM; k0 += 32) {
    const int ko = (k0 >> 5) * 512;
    f16x8 a[4], b[4];
    #pragma unroll
    for (int m = 0; m < 4; ++m) a[m] = *(const f16x8*)(pa[m] + ko);
    #pragma unroll
    for (int n = 0; n < 4; ++n) b[n] = *(const f16x8*)(pb[n] + ko);
    #pragma unroll
    for (int m = 0; m < 4; ++m)
      #pragma unroll
      for (int n = 0; n < 4; ++n)
        acc[m][n] = __builtin_amdgcn_mfma_f32_16x16x32_f16(a[m], b[n], acc[m][n], 0, 0, 0);
  }

  // epilogue: per 64-row half, LDS-transpose then stream full rows out
  float* base = out0 + (size_t)(ys * NSET + xs) * NITEM * NITEM;
  #pragma unroll
  for (int half = 0; half < 2; ++half) {
    if ((w & 1) == half) {             // waves owning i-range [half*64, half*64+64)
      #pragma unroll
      for (int m = 0; m < 4; ++m)
        #pragma unroll
        for (int n = 0; n < 4; ++n) {
          int il = n * 16 + la;                     // local i: 0..63
          int jb = (wj + m * 16 + lb * 4) * 4;      // byte offset along j
          *(f32x4*)((char*)hbuf + il * 512 + (jb ^ ((il & 15) << 4))) = acc[m][n];
        }
    }
    __syncthreads();
    #pragma unroll
    for (int c = 0; c < 8; ++c) {      // each wave streams 16 rows, 2 rows/instr
      int il = w * 16 + c * 2 + (lane >> 5);
      int jb = (lane & 31) * 16;
      f32x4 v = *(const f32x4*)((char*)hbuf + il * 512 + (jb ^ ((il & 15) << 4)));
      __builtin_nontemporal_store(v, (f32x4*)(base + (size_t)(half * 64 + il) * NITEM) + (lane & 31));
    }
    __syncthreads();
  }
}

// ---------------- score kernel: one block per (ys,xs) ----------------
__global__ __launch_bounds__(256, 2) void k_score(const f16* __restrict__ LXY_F,
                                                  const float* __restrict__ nItem,
                                                  const float* __restrict__ w2,
                                                  float* __restrict__ out1) {
  __shared__ float red[4][4];
  const int bid = blockIdx.x;
  const int ys = bid / NSET, xs = bid % NSET;
  const int tid = threadIdx.x, w = tid >> 6, lane = tid & 63;
  const int wj = (w >> 1) * 64;        // j (y item) range -> A operand
  const int wi = (w & 1) * 64;         // i (x item) range -> B operand

  const f16* pa[4];
  const f16* pb[4];
  #pragma unroll
  for (int m = 0; m < 4; ++m)
    pa[m] = LXY_F + (48 + ys) * SETH + ((wj >> 4) + m) * 4096 + lane * 8;
  #pragma unroll
  for (int n = 0; n < 4; ++n)
    pb[n] = LXY_F + xs * SETH + ((wi >> 4) + n) * 4096 + lane * 8;

  float rsum[HEADS];
  #pragma unroll
  for (int h = 0; h < HEADS; ++h) {
    f32x4 acc[4][4] = {};
    #pragma unroll
    for (int kk = 0; kk < 2; ++kk) {             // K=64 per head; relu AFTER full K
      const int ko = ((h * 64 + kk * 32) >> 5) * 512;
      f16x8 a[4], b[4];
      #pragma unroll
      for (int m = 0; m < 4; ++m) a[m] = *(const f16x8*)(pa[m] + ko);
      #pragma unroll
      for (int n = 0; n < 4; ++n) b[n] = *(const f16x8*)(pb[n] + ko);
      #pragma unroll
      for (int m = 0; m < 4; ++m)
        #pragma unroll
        for (int n = 0; n < 4; ++n)
          acc[m][n] = __builtin_amdgcn_mfma_f32_16x16x32_f16(a[m], b[n], acc[m][n], 0, 0, 0);
    }
    float s = 0.f;
    #pragma unroll
    for (int m = 0; m < 4; ++m)
      #pragma unroll
      for (int n = 0; n < 4; ++n)
        #pragma unroll
        for (int r = 0; r < 4; ++r) s += fmaxf(acc[m][n][r], 0.f);
    rsum[h] = s;
  }
  #pragma unroll
  for (int off = 32; off >= 1; off >>= 1)
    #pragma unroll
    for (int h = 0; h < HEADS; ++h) rsum[h] += __shfl_xor(rsum[h], off);
  if (lane == 0) {
    #pragma unroll
    for (int h = 0; h < HEADS; ++h) red[w][h] = rsum[h];
  }
  __syncthreads();
  if (tid == 0) {
    // relu(S/8) summed == (sum relu(S))/8 ; then / nItem[x] / nItem[y]; then @ w2
    float inv = 1.0f / (8.0f * nItem[xs] * nItem[ys]);
    float sc = 0.f;
    #pragma unroll
    for (int h = 0; h < HEADS; ++h)
      sc += (red[0][h] + red[1][h] + red[2][h] + red[3][h]) * inv * w2[h];
    out1[ys * NSET + xs] = sc;
  }
}

// ---------------- launch ----------------
extern "C" void kernel_launch(void* const* d_in, const int* in_sizes, int n_in,
                              void* d_out, int out_size, void* d_ws, size_t ws_size,
                              hipStream_t stream) {
  const float* x     = (const float*)d_in[0];
  const float* y     = (const float*)d_in[1];
  const float* nItem = (const float*)d_in[2];
  const float* W     = (const float*)d_in[3];
  const float* w2    = (const float*)d_in[4];
  float* out0 = (float*)d_out;
  float* out1 = out0 + (size_t)NSET * NSET * NITEM * NITEM;

  char* ws = (char*)d_ws;
  f16* XYN_F = (f16*)ws;
  f16* XYH_F = (f16*)(ws + OFF_XYH);
  f16* WT_F  = (f16*)(ws + OFF_WT);
  f16* LXY_F = (f16*)(ws + OFF_LXY);

  k_wt<<<256, 256, 0, stream>>>(W, WT_F);
  k_norm<<<(2 * NROWS) / 4, 256, 0, stream>>>(x, y, XYN_F, XYH_F);
  k_proj<<<192, 256, 0, stream>>>(XYH_F, WT_F, LXY_F);
  k_cos<<<NSET * NSET, 256, 0, stream>>>(XYN_F, out0);
  k_score<<<NSET * NSET, 256, 0, stream>>>(LXY_F, nItem, w2, out1);
}